// Round 1
// baseline (2993.527 us; speedup 1.0000x reference)
//
#include <hip/hip_runtime.h>
#include <hip/hip_bf16.h>

constexpr int Bc   = 16;
constexpr int DIMc = 384;
constexpr int Rc   = 28;
constexpr int NHc  = 8;
constexpr int KDc  = 32;
constexpr int Dc   = 128;
constexpr int DHc  = 1024;   // NH*D
constexpr int Nc   = 784;    // R*R
constexpr float SCALEf = 0.17677669529663687f;  // 32^-0.5
constexpr float EPSf   = 1e-5f;

// ---------------------------------------------------------------------------
// Generic 1x1-conv GEMM + BatchNorm epilogue.
//   Y[b,o,n]  = (sum_i W[o,i]*Xeff[b,i,n] + bias[o]) * inv[o] + shift[o]
//   Xeff      = X            (X2 == nullptr)
//             = relu(X + X2) (X2 != nullptr)
// Optional transposed store Yt[b,h,n,d] with o = h*128+d (used for v so the
// attention PV loop gets coalesced reads).
// Tiles: 64 o x 64 j (j = b*784+n flattened), K-chunks of 16.
// 784 % 4 == 0 so any 4-aligned j-quad never straddles a batch boundary.
// ---------------------------------------------------------------------------
__global__ __launch_bounds__(256) void gemm_bn_kernel(
    const float* __restrict__ W, const float* __restrict__ X,
    const float* __restrict__ X2,
    const float* __restrict__ bias, const float* __restrict__ gg,
    const float* __restrict__ bet, const float* __restrict__ mea,
    const float* __restrict__ rv,
    float* __restrict__ Y, float* __restrict__ Yt,
    int O, int K)
{
    __shared__ __align__(16) float As[16][68];   // [k][o]
    __shared__ __align__(16) float Bs[16][68];   // [k][j]
    __shared__ float Ys[64][65];                 // transpose staging

    const int t  = threadIdx.x;
    const int j0 = blockIdx.x * 64;
    const int o0 = blockIdx.y * 64;
    const int tx = t & 15, ty = t >> 4;

    // B-tile load slot: row kk_b, cols jj_b..jj_b+3 (float4)
    const int kk_b = t >> 4;
    const int jj_b = (t & 15) * 4;
    const int jB   = j0 + jj_b;
    const int bB   = jB / Nc;
    const int nB   = jB - bB * Nc;
    const float* xb  = X + ((size_t)bB * K) * Nc + nB;
    const float* xb2 = (X2 != nullptr) ? X2 + ((size_t)bB * K) * Nc + nB : nullptr;

    // A-tile load slot: row o_a, cols kk_a..kk_a+3 of W (float4)
    const int o_a  = t >> 2;
    const int kk_a = (t & 3) * 4;
    const float* wp = W + (size_t)(o0 + o_a) * K + kk_a;

    float acc[4][4] = {};

    for (int k0 = 0; k0 < K; k0 += 16) {
        float4 a4 = *reinterpret_cast<const float4*>(wp + k0);
        As[kk_a + 0][o_a] = a4.x;
        As[kk_a + 1][o_a] = a4.y;
        As[kk_a + 2][o_a] = a4.z;
        As[kk_a + 3][o_a] = a4.w;

        float4 b4 = *reinterpret_cast<const float4*>(xb + (size_t)(k0 + kk_b) * Nc);
        if (X2 != nullptr) {
            float4 u = *reinterpret_cast<const float4*>(xb2 + (size_t)(k0 + kk_b) * Nc);
            b4.x = fmaxf(b4.x + u.x, 0.f);
            b4.y = fmaxf(b4.y + u.y, 0.f);
            b4.z = fmaxf(b4.z + u.z, 0.f);
            b4.w = fmaxf(b4.w + u.w, 0.f);
        }
        *reinterpret_cast<float4*>(&Bs[kk_b][jj_b]) = b4;
        __syncthreads();

        #pragma unroll
        for (int kk = 0; kk < 16; kk++) {
            float4 av = *reinterpret_cast<const float4*>(&As[kk][ty * 4]);
            float4 bv = *reinterpret_cast<const float4*>(&Bs[kk][tx * 4]);
            float aa[4] = {av.x, av.y, av.z, av.w};
            float bb[4] = {bv.x, bv.y, bv.z, bv.w};
            #pragma unroll
            for (int oi = 0; oi < 4; oi++)
                #pragma unroll
                for (int ji = 0; ji < 4; ji++)
                    acc[oi][ji] += aa[oi] * bb[ji];
        }
        __syncthreads();
    }

    if (Y != nullptr) {
        const int jS = j0 + tx * 4;
        const int bS = jS / Nc;
        const int nS = jS - bS * Nc;
        #pragma unroll
        for (int oi = 0; oi < 4; oi++) {
            int o = o0 + ty * 4 + oi;
            float inv = gg[o] / sqrtf(rv[o] + EPSf);
            float sh  = bet[o] - mea[o] * inv + bias[o] * inv;
            float4 r4;
            r4.x = acc[oi][0] * inv + sh;
            r4.y = acc[oi][1] * inv + sh;
            r4.z = acc[oi][2] * inv + sh;
            r4.w = acc[oi][3] * inv + sh;
            *reinterpret_cast<float4*>(&Y[((size_t)bS * O + o) * Nc + nS]) = r4;
        }
    }
    if (Yt != nullptr) {
        #pragma unroll
        for (int oi = 0; oi < 4; oi++) {
            int o = o0 + ty * 4 + oi;
            float inv = gg[o] / sqrtf(rv[o] + EPSf);
            float sh  = bet[o] - mea[o] * inv + bias[o] * inv;
            #pragma unroll
            for (int ji = 0; ji < 4; ji++)
                Ys[ty * 4 + oi][tx * 4 + ji] = acc[oi][ji] * inv + sh;
        }
        __syncthreads();
        // coalesced transposed store: 64 consecutive lanes write 64 consecutive d
        #pragma unroll
        for (int rep = 0; rep < 16; rep++) {
            int lin = rep * 256 + t;
            int ol  = lin & 63;
            int jj  = lin >> 6;
            int o   = o0 + ol;
            int j   = j0 + jj;
            int bb2 = j / Nc, n2 = j - bb2 * Nc;
            int h = o >> 7, d = o & 127;
            Yt[(((size_t)bb2 * NHc + h) * Nc + n2) * Dc + d] = Ys[ol][jj];
        }
    }
}

// ---------------------------------------------------------------------------
// Depthwise 3x3 conv + BN. Reads v in transposed (B,H,N,D) layout (d-fastest
// -> coalesced), writes v_local in natural (B,DH,N) layout as float4 over x.
// ---------------------------------------------------------------------------
__global__ __launch_bounds__(128) void dwconv_bn_kernel(
    const float* __restrict__ vt, const float* __restrict__ wl,
    const float* __restrict__ bl, const float* __restrict__ gg,
    const float* __restrict__ bet, const float* __restrict__ mea,
    const float* __restrict__ rv, float* __restrict__ vloc)
{
    const int d  = threadIdx.x;         // 0..127
    const int x0 = blockIdx.x * 4;      // 0,4,...,24
    const int y  = blockIdx.y;          // 0..27
    const int bh = blockIdx.z;          // b*8+h
    const int h  = bh & 7;
    const int c  = h * Dc + d;

    float wreg[9];
    #pragma unroll
    for (int i = 0; i < 9; i++) wreg[i] = wl[c * 9 + i];

    const float* base = vt + (size_t)bh * Nc * Dc + d;

    float res[4];
    #pragma unroll
    for (int i = 0; i < 4; i++) {
        int x = x0 + i;
        float a = 0.f;
        #pragma unroll
        for (int dy = -1; dy <= 1; dy++) {
            int yy = y + dy;
            if ((unsigned)yy >= (unsigned)Rc) continue;
            #pragma unroll
            for (int dx = -1; dx <= 1; dx++) {
                int xx = x + dx;
                if ((unsigned)xx >= (unsigned)Rc) continue;
                a += base[(size_t)(yy * Rc + xx) * Dc] * wreg[(dy + 1) * 3 + (dx + 1)];
            }
        }
        res[i] = a + bl[c];
    }
    float inv = gg[c] / sqrtf(rv[c] + EPSf);
    float sh  = bet[c] - mea[c] * inv;
    float4 r4;
    r4.x = res[0] * inv + sh;
    r4.y = res[1] * inv + sh;
    r4.z = res[2] * inv + sh;
    r4.w = res[3] * inv + sh;
    const int bb = bh >> 3;
    *reinterpret_cast<float4*>(&vloc[((size_t)bb * DHc + c) * Nc + y * Rc + x0]) = r4;
}

// ---------------------------------------------------------------------------
// Fused attention: per (batch, 4-row tile), all 8 heads (talking-heads mixes
// heads pre- and post-softmax so heads cannot be split across blocks).
// S[8][4][784] fp32 lives in LDS (~100 KB -> 1 block/CU).
// Phases: QK^T+bias -> TH1 -> softmax -> TH2*invsum -> PV.
// ---------------------------------------------------------------------------
__global__ __launch_bounds__(256) void attn_kernel(
    const float* __restrict__ qg, const float* __restrict__ kg,
    const float* __restrict__ vt, const float* __restrict__ btab,
    const int* __restrict__ bidx,
    const float* __restrict__ th1w, const float* __restrict__ th1b,
    const float* __restrict__ th2w, const float* __restrict__ th2b,
    float* __restrict__ outp)
{
    __shared__ __align__(16) float S[NHc][4][Nc];     // 100352 B
    __shared__ __align__(16) float qs[NHc][KDc][4];   // 4 KB, SCALE folded in
    __shared__ float w1[64], w2[64], b1v[8], b2v[8];
    __shared__ float invs[NHc][4];

    const int t  = threadIdx.x;
    const int b  = blockIdx.y;
    const int n0 = blockIdx.x * 4;

    // load q tile (transposed into [h][c][r]), fold in SCALE
    for (int i = t; i < NHc * KDc * 4; i += 256) {
        int h = i >> 7, c = (i >> 2) & 31, r = i & 3;
        qs[h][c][r] = qg[((size_t)(b * NHc + h) * KDc + c) * Nc + n0 + r] * SCALEf;
    }
    if (t < 64)       w1[t]        = th1w[t];
    else if (t < 128) w2[t - 64]   = th2w[t - 64];
    else if (t < 136) b1v[t - 128] = th1b[t - 128];
    else if (t < 144) b2v[t - 136] = th2b[t - 136];
    __syncthreads();

    // ---- Phase 1: QK^T (scaled) + relative-position bias ----
    for (int m = t; m < Nc; m += 256) {
        int ir[4];
        #pragma unroll
        for (int r = 0; r < 4; r++) ir[r] = bidx[(n0 + r) * Nc + m];
        for (int h = 0; h < NHc; h++) {
            const float* kp = kg + ((size_t)(b * NHc + h) * KDc) * Nc + m;
            float sx = 0.f, sy = 0.f, sz = 0.f, sw = 0.f;
            #pragma unroll
            for (int c = 0; c < KDc; c++) {
                float kv = kp[(size_t)c * Nc];
                float4 q4 = *reinterpret_cast<const float4*>(&qs[h][c][0]);
                sx += q4.x * kv; sy += q4.y * kv;
                sz += q4.z * kv; sw += q4.w * kv;
            }
            S[h][0][m] = sx + btab[h * Nc + ir[0]];
            S[h][1][m] = sy + btab[h * Nc + ir[1]];
            S[h][2][m] = sz + btab[h * Nc + ir[2]];
            S[h][3][m] = sw + btab[h * Nc + ir[3]];
        }
    }
    __syncthreads();

    // ---- Phase 2: talking-heads 1 (in-place, each (r,m) owned by 1 thread) ----
    for (int m = t; m < Nc; m += 256) {
        #pragma unroll
        for (int r = 0; r < 4; r++) {
            float a[8];
            #pragma unroll
            for (int i = 0; i < 8; i++) a[i] = S[i][r][m];
            #pragma unroll
            for (int o = 0; o < 8; o++) {
                float s = b1v[o];
                #pragma unroll
                for (int i = 0; i < 8; i++) s += w1[o * 8 + i] * a[i];
                S[o][r][m] = s;
            }
        }
    }
    __syncthreads();

    // ---- Phase 3: softmax stats (32 rows x 8 lanes each) ----
    {
        const int row = t >> 3;          // 0..31
        const int h = row >> 2, r = row & 3, sub = t & 7;
        float mx = -1e30f;
        for (int m = sub; m < Nc; m += 8) mx = fmaxf(mx, S[h][r][m]);
        #pragma unroll
        for (int off = 1; off < 8; off <<= 1) mx = fmaxf(mx, __shfl_xor(mx, off));
        float sum = 0.f;
        for (int m = sub; m < Nc; m += 8) {
            float e = __expf(S[h][r][m] - mx);
            S[h][r][m] = e;
            sum += e;
        }
        #pragma unroll
        for (int off = 1; off < 8; off <<= 1) sum += __shfl_xor(sum, off);
        if (sub == 0) invs[h][r] = 1.0f / sum;
    }
    __syncthreads();

    // ---- Phase 4: normalize + talking-heads 2 (in-place) ----
    for (int m = t; m < Nc; m += 256) {
        #pragma unroll
        for (int r = 0; r < 4; r++) {
            float a[8];
            #pragma unroll
            for (int i = 0; i < 8; i++) a[i] = S[i][r][m] * invs[i][r];
            #pragma unroll
            for (int o = 0; o < 8; o++) {
                float s = b2v[o];
                #pragma unroll
                for (int i = 0; i < 8; i++) s += w2[o * 8 + i] * a[i];
                S[o][r][m] = s;
            }
        }
    }
    __syncthreads();

    // ---- Phase 5: PV. Lane d, o split across block halves; S reads are
    //      wave-broadcast b128, v reads lane-coalesced (transposed layout). ----
    {
        const int d  = t & 127;
        const int og = t >> 7;           // 0 or 1 (uniform per wave)
        #pragma unroll
        for (int oo = 0; oo < 4; oo++) {
            const int o = oo * 2 + og;
            const float* vp = vt + ((size_t)(b * NHc + o) * Nc) * Dc + d;
            float a0 = 0.f, a1 = 0.f, a2 = 0.f, a3 = 0.f;
            for (int m = 0; m < Nc; m += 4) {
                float4 s0 = *reinterpret_cast<const float4*>(&S[o][0][m]);
                float4 s1 = *reinterpret_cast<const float4*>(&S[o][1][m]);
                float4 s2 = *reinterpret_cast<const float4*>(&S[o][2][m]);
                float4 s3 = *reinterpret_cast<const float4*>(&S[o][3][m]);
                float v0 = vp[(size_t)(m + 0) * Dc];
                float v1 = vp[(size_t)(m + 1) * Dc];
                float v2 = vp[(size_t)(m + 2) * Dc];
                float v3 = vp[(size_t)(m + 3) * Dc];
                a0 += s0.x * v0 + s0.y * v1 + s0.z * v2 + s0.w * v3;
                a1 += s1.x * v0 + s1.y * v1 + s1.z * v2 + s1.w * v3;
                a2 += s2.x * v0 + s2.y * v1 + s2.z * v2 + s2.w * v3;
                a3 += s3.x * v0 + s3.y * v1 + s3.z * v2 + s3.w * v3;
            }
            float4 res; res.x = a0; res.y = a1; res.z = a2; res.w = a3;
            *reinterpret_cast<float4*>(
                &outp[((size_t)b * DHc + o * Dc + d) * Nc + n0]) = res;
        }
    }
}

// ---------------------------------------------------------------------------
extern "C" void kernel_launch(void* const* d_in, const int* in_sizes, int n_in,
                              void* d_out, int out_size, void* d_ws, size_t ws_size,
                              hipStream_t stream)
{
    const float* x    = (const float*)d_in[0];
    const float* q_w  = (const float*)d_in[1];
    const float* q_b  = (const float*)d_in[2];
    const float* q_g  = (const float*)d_in[3];
    const float* q_be = (const float*)d_in[4];
    const float* q_m  = (const float*)d_in[5];
    const float* q_rv = (const float*)d_in[6];
    const float* k_w  = (const float*)d_in[7];
    const float* k_b  = (const float*)d_in[8];
    const float* k_g  = (const float*)d_in[9];
    const float* k_be = (const float*)d_in[10];
    const float* k_m  = (const float*)d_in[11];
    const float* k_rv = (const float*)d_in[12];
    const float* v_w  = (const float*)d_in[13];
    const float* v_b  = (const float*)d_in[14];
    const float* v_g  = (const float*)d_in[15];
    const float* v_be = (const float*)d_in[16];
    const float* v_m  = (const float*)d_in[17];
    const float* v_rv = (const float*)d_in[18];
    const float* vl_w = (const float*)d_in[19];
    const float* vl_b = (const float*)d_in[20];
    const float* vl_g = (const float*)d_in[21];
    const float* vl_be= (const float*)d_in[22];
    const float* vl_m = (const float*)d_in[23];
    const float* vl_rv= (const float*)d_in[24];
    const float* th1w = (const float*)d_in[25];
    const float* th1b = (const float*)d_in[26];
    const float* th2w = (const float*)d_in[27];
    const float* th2b = (const float*)d_in[28];
    const float* p_w  = (const float*)d_in[29];
    const float* p_b  = (const float*)d_in[30];
    const float* p_g  = (const float*)d_in[31];
    const float* p_be = (const float*)d_in[32];
    const float* p_m  = (const float*)d_in[33];
    const float* p_rv = (const float*)d_in[34];
    const float* btab = (const float*)d_in[35];
    const int*   bidx = (const int*)d_in[36];

    float* ws   = (float*)d_ws;
    float* qb   = ws;                                   // (B,256,784)
    float* kb   = qb   + (size_t)Bc * NHc * KDc * Nc;   // (B,256,784)
    float* vtb  = kb   + (size_t)Bc * NHc * KDc * Nc;   // (B,H,N,D) transposed
    float* vloc = vtb  + (size_t)Bc * DHc * Nc;         // (B,1024,784)
    float* atto = vloc + (size_t)Bc * DHc * Nc;         // (B,1024,784)

    gemm_bn_kernel<<<dim3(196, 4), 256, 0, stream>>>(
        q_w, x, nullptr, q_b, q_g, q_be, q_m, q_rv, qb, nullptr, NHc * KDc, DIMc);
    gemm_bn_kernel<<<dim3(196, 4), 256, 0, stream>>>(
        k_w, x, nullptr, k_b, k_g, k_be, k_m, k_rv, kb, nullptr, NHc * KDc, DIMc);
    gemm_bn_kernel<<<dim3(196, 16), 256, 0, stream>>>(
        v_w, x, nullptr, v_b, v_g, v_be, v_m, v_rv, nullptr, vtb, DHc, DIMc);
    dwconv_bn_kernel<<<dim3(7, 28, Bc * NHc), 128, 0, stream>>>(
        vtb, vl_w, vl_b, vl_g, vl_be, vl_m, vl_rv, vloc);
    attn_kernel<<<dim3(196, Bc), 256, 0, stream>>>(
        qb, kb, vtb, btab, bidx, th1w, th1b, th2w, th2b, atto);
    gemm_bn_kernel<<<dim3(196, 6), 256, 0, stream>>>(
        p_w, atto, vloc, p_b, p_g, p_be, p_m, p_rv, (float*)d_out, nullptr, DIMc, DHc);
}

// Round 5
// 855.592 us; speedup vs baseline: 3.4988x; 3.4988x over previous
//
#include <hip/hip_runtime.h>
#include <hip/hip_bf16.h>

typedef unsigned short u16;
typedef u16   u16x4 __attribute__((ext_vector_type(4)));
typedef u16   u16x8 __attribute__((ext_vector_type(8)));
typedef short s16x4 __attribute__((ext_vector_type(4)));
typedef short s16x8 __attribute__((ext_vector_type(8)));
typedef float f32x16 __attribute__((ext_vector_type(16)));

constexpr int Bc   = 16;
constexpr int DIMc = 384;
constexpr int Rc   = 28;
constexpr int NHc  = 8;
constexpr int KDc  = 32;
constexpr int Dc   = 128;
constexpr int DHc  = 1024;   // NH*D
constexpr int Nc   = 784;    // R*R
constexpr int Mrows = NHc * Nc;  // 6272 = flattened (o,n) rows per batch
constexpr int BPASS = 4;         // batches per attention pass (SSb reuse)
constexpr float SCALEf = 0.17677669529663687f;  // 32^-0.5
constexpr float EPSf   = 1e-5f;

__device__ inline float bf2f(u16 u) {
    union { float f; unsigned i; } c; c.i = ((unsigned)u) << 16; return c.f;
}
__device__ inline u16 f2bf(float f) {
    union { float f; unsigned u; } c; c.f = f;
    unsigned r = c.u + 0x7fffu + ((c.u >> 16) & 1u);   // RNE
    return (u16)(r >> 16);
}
__device__ inline f32x16 zero16() {
    f32x16 z;
    #pragma unroll
    for (int i = 0; i < 16; i++) z[i] = 0.f;
    return z;
}
__device__ inline s16x8 ldfrag(const u16* p) {
    s16x4 lo = *(const s16x4*)p;
    s16x4 hi = *(const s16x4*)(p + 4);
    return __builtin_shufflevector(lo, hi, 0, 1, 2, 3, 4, 5, 6, 7);
}
__device__ inline f32x16 mfma32(s16x8 a, s16x8 b, f32x16 c) {
    return __builtin_amdgcn_mfma_f32_32x32x16_bf16(a, b, c, 0, 0, 0);
}

// ---------------------------------------------------------------------------
// mbias[o*784+n][m] = sum_i th1w[o,i]*btab[i, bidx[n,m]] + th1b[o]   (fp32)
// ---------------------------------------------------------------------------
__global__ __launch_bounds__(256) void bias_mix_kernel(
    const float* __restrict__ btab, const int* __restrict__ bidx,
    const float* __restrict__ w1, const float* __restrict__ b1,
    float* __restrict__ mbias)
{
    __shared__ float w1s[64], b1s[8];
    const int t = threadIdx.x;
    if (t < 64) w1s[t] = w1[t];
    if (t < 8)  b1s[t] = b1[t];
    __syncthreads();
    int e = blockIdx.x * 256 + t;          // quad index over n*196
    if (e >= Nc * (Nc / 4)) return;
    int n  = e / (Nc / 4);
    int mq = (e - n * (Nc / 4)) * 4;
    int4 g = *reinterpret_cast<const int4*>(&bidx[n * Nc + mq]);
    float gv[8][4];
    #pragma unroll
    for (int i = 0; i < 8; i++) {
        gv[i][0] = btab[i * Nc + g.x];
        gv[i][1] = btab[i * Nc + g.y];
        gv[i][2] = btab[i * Nc + g.z];
        gv[i][3] = btab[i * Nc + g.w];
    }
    #pragma unroll
    for (int o = 0; o < 8; o++) {
        float4 r;
        float* rp = &r.x;
        #pragma unroll
        for (int q = 0; q < 4; q++) {
            float s = b1s[o];
            #pragma unroll
            for (int i = 0; i < 8; i++) s += w1s[o * 8 + i] * gv[i][q];
            rp[q] = s;
        }
        *reinterpret_cast<float4*>(&mbias[((size_t)o * Nc + n) * Nc + mq]) = r;
    }
}

// ---------------------------------------------------------------------------
// fp32 VALU GEMM + BN, mode-specific epilogues.
// MODE 1 (T):  Xf fp32 in; Yb[b][j][ik] bf16 = scale*bn(...)  (transposed)
// MODE 2 (N):  Xf fp32 in; Yb[b][o][n]  bf16 = bn(...)        (natural)
// MODE 3 (P):  Xb bf16 + X2b bf16 in, relu(X+X2); Yf fp32 out (natural)
// ---------------------------------------------------------------------------
template<int MODE>
__global__ __launch_bounds__(256) void gemm_bn(
    const float* __restrict__ W,  const float* __restrict__ Xf,
    const u16* __restrict__ Xb,   const u16* __restrict__ X2b,
    const float* __restrict__ bias, const float* __restrict__ gg,
    const float* __restrict__ bet, const float* __restrict__ mea,
    const float* __restrict__ rvv, float scale,
    float* __restrict__ Yf, u16* __restrict__ Yb, int O, int K)
{
    __shared__ __align__(16) float As[16][68];   // [k][o]
    __shared__ __align__(16) float Bs[16][68];   // [k][j]
    __shared__ float Ys[64][65];                 // transpose staging

    const int t  = threadIdx.x;
    const int j0 = blockIdx.x * 64;
    const int o0 = blockIdx.y * 64;
    const int tx = t & 15, ty = t >> 4;

    const int kk_b = t >> 4;
    const int jj_b = (t & 15) * 4;
    const int jB   = j0 + jj_b;
    const int bB   = jB / Nc;
    const int nB   = jB - bB * Nc;
    const float* xf  = (MODE != 3) ? Xf + ((size_t)bB * K) * Nc + nB : nullptr;
    const u16*   xbb = (MODE == 3) ? Xb  + ((size_t)bB * K) * Nc + nB : nullptr;
    const u16*   xb2 = (MODE == 3) ? X2b + ((size_t)bB * K) * Nc + nB : nullptr;

    const int o_a  = t >> 2;
    const int kk_a = (t & 3) * 4;
    const float* wp = W + (size_t)(o0 + o_a) * K + kk_a;

    float acc[4][4] = {};

    for (int k0 = 0; k0 < K; k0 += 16) {
        float4 a4 = *reinterpret_cast<const float4*>(wp + k0);
        As[kk_a + 0][o_a] = a4.x;
        As[kk_a + 1][o_a] = a4.y;
        As[kk_a + 2][o_a] = a4.z;
        As[kk_a + 3][o_a] = a4.w;

        float4 b4;
        if (MODE == 3) {
            u16x4 ua = *reinterpret_cast<const u16x4*>(&xbb[(size_t)(k0 + kk_b) * Nc]);
            u16x4 u2 = *reinterpret_cast<const u16x4*>(&xb2[(size_t)(k0 + kk_b) * Nc]);
            b4.x = fmaxf(bf2f(ua[0]) + bf2f(u2[0]), 0.f);
            b4.y = fmaxf(bf2f(ua[1]) + bf2f(u2[1]), 0.f);
            b4.z = fmaxf(bf2f(ua[2]) + bf2f(u2[2]), 0.f);
            b4.w = fmaxf(bf2f(ua[3]) + bf2f(u2[3]), 0.f);
        } else {
            b4 = *reinterpret_cast<const float4*>(xf + (size_t)(k0 + kk_b) * Nc);
        }
        *reinterpret_cast<float4*>(&Bs[kk_b][jj_b]) = b4;
        __syncthreads();

        #pragma unroll
        for (int kk = 0; kk < 16; kk++) {
            float4 av = *reinterpret_cast<const float4*>(&As[kk][ty * 4]);
            float4 bv = *reinterpret_cast<const float4*>(&Bs[kk][tx * 4]);
            float aa[4] = {av.x, av.y, av.z, av.w};
            float bb[4] = {bv.x, bv.y, bv.z, bv.w};
            #pragma unroll
            for (int oi = 0; oi < 4; oi++)
                #pragma unroll
                for (int ji = 0; ji < 4; ji++)
                    acc[oi][ji] += aa[oi] * bb[ji];
        }
        __syncthreads();
    }

    if (MODE == 3) {
        const int jS = j0 + tx * 4;
        const int bS = jS / Nc;
        const int nS = jS - bS * Nc;
        #pragma unroll
        for (int oi = 0; oi < 4; oi++) {
            int o = o0 + ty * 4 + oi;
            float inv = gg[o] / sqrtf(rvv[o] + EPSf);
            float sh  = bet[o] - mea[o] * inv + bias[o] * inv;
            float4 r4;
            r4.x = acc[oi][0] * inv + sh;
            r4.y = acc[oi][1] * inv + sh;
            r4.z = acc[oi][2] * inv + sh;
            r4.w = acc[oi][3] * inv + sh;
            *reinterpret_cast<float4*>(&Yf[((size_t)bS * O + o) * Nc + nS]) = r4;
        }
    } else if (MODE == 2) {
        const int jS = j0 + tx * 4;
        const int bS = jS / Nc;
        const int nS = jS - bS * Nc;
        #pragma unroll
        for (int oi = 0; oi < 4; oi++) {
            int o = o0 + ty * 4 + oi;
            float inv = gg[o] / sqrtf(rvv[o] + EPSf);
            float sh  = bet[o] - mea[o] * inv + bias[o] * inv;
            u16x4 r4;
            r4[0] = f2bf(acc[oi][0] * inv + sh);
            r4[1] = f2bf(acc[oi][1] * inv + sh);
            r4[2] = f2bf(acc[oi][2] * inv + sh);
            r4[3] = f2bf(acc[oi][3] * inv + sh);
            *reinterpret_cast<u16x4*>(&Yb[((size_t)bS * O + o) * Nc + nS]) = r4;
        }
    } else {   // MODE 1: transposed bf16 store, scale folded
        #pragma unroll
        for (int oi = 0; oi < 4; oi++) {
            int o = o0 + ty * 4 + oi;
            float inv = gg[o] / sqrtf(rvv[o] + EPSf);
            float sh  = bet[o] - mea[o] * inv + bias[o] * inv;
            #pragma unroll
            for (int ji = 0; ji < 4; ji++)
                Ys[ty * 4 + oi][tx * 4 + ji] = acc[oi][ji] * inv + sh;
        }
        __syncthreads();
        #pragma unroll
        for (int rep = 0; rep < 16; rep++) {
            int lin = rep * 256 + t;
            int ol  = lin & 63;        // ik within tile
            int jj  = lin >> 6;        // j within tile
            int j   = j0 + jj;
            int bb2 = j / Nc, nn = j - bb2 * Nc;
            int ik  = o0 + ol;
            Yb[((size_t)bb2 * Nc + nn) * 256 + ik] = f2bf(Ys[ol][jj] * scale);
        }
    }
}

// ---------------------------------------------------------------------------
// Depthwise 3x3 + BN, natural layout, bf16 in/out. One block per (b,c).
// ---------------------------------------------------------------------------
__global__ __launch_bounds__(256) void dwconv_bn_kernel(
    const u16* __restrict__ vnat, const float* __restrict__ wl,
    const float* __restrict__ bl, const float* __restrict__ gg,
    const float* __restrict__ bet, const float* __restrict__ mea,
    const float* __restrict__ rvv, u16* __restrict__ vloc)
{
    __shared__ float img[30][30];
    const int t = threadIdx.x;
    const int b = blockIdx.x >> 10;
    const int c = blockIdx.x & 1023;
    const u16* src = vnat + ((size_t)b * DHc + c) * Nc;

    for (int i = t; i < 900; i += 256) img[i / 30][i % 30] = 0.f;
    __syncthreads();
    if (t < 196) {
        u16x4 u = *reinterpret_cast<const u16x4*>(&src[t * 4]);
        int y = (t * 4) / 28, x = (t * 4) % 28;
        img[y + 1][x + 1] = bf2f(u[0]);
        img[y + 1][x + 2] = bf2f(u[1]);
        img[y + 1][x + 3] = bf2f(u[2]);
        img[y + 1][x + 4] = bf2f(u[3]);
    }
    __syncthreads();

    float wreg[9];
    #pragma unroll
    for (int i = 0; i < 9; i++) wreg[i] = wl[c * 9 + i];
    float inv = gg[c] / sqrtf(rvv[c] + EPSf);
    float sh  = bet[c] - mea[c] * inv + bl[c] * inv;

    for (int i = t; i < Nc; i += 256) {
        int y = i / 28, x = i % 28;
        float a = 0.f;
        #pragma unroll
        for (int dy = 0; dy < 3; dy++)
            #pragma unroll
            for (int dx = 0; dx < 3; dx++)
                a += img[y + dy][x + dx] * wreg[dy * 3 + dx];
        vloc[((size_t)b * DHc + c) * Nc + i] = f2bf(a * inv + sh);
    }
}

// ---------------------------------------------------------------------------
// Scores with folded TH1:
//   SS[lb][Mr][m] = sum_ik w1[o, ik>>5]*qs[gb][n][ik] * Kt[gb][m][ik] + mbias
// where Mr = o*784+n = M0+row. w1 applied during A staging (magic-div by 784).
// ---------------------------------------------------------------------------
__global__ __launch_bounds__(256) void scores_kernel(
    const u16* __restrict__ qsb, const u16* __restrict__ Kt,
    const float* __restrict__ th1w, const float* __restrict__ mbias,
    u16* __restrict__ SSb, int b0)
{
    __shared__ u16 Asb[128][36];
    __shared__ u16 Bsb[128][36];
    __shared__ float w1s[64];
    const int t  = threadIdx.x;
    const int m0 = blockIdx.x * 128;
    const int M0 = blockIdx.y * 128;
    const int lb = blockIdx.z;           // local batch in pass
    const int gb = b0 + lb;              // global batch
    const int w = t >> 6, l = t & 63;
    const int lrow = l & 31, lhalf = l >> 5;
    const int Msub = w & 1, msub = w >> 1;

    if (t < 64) w1s[t] = th1w[t];
    __syncthreads();

    f32x16 acc[2][2];
    acc[0][0] = zero16(); acc[0][1] = zero16();
    acc[1][0] = zero16(); acc[1][1] = zero16();

    for (int kc = 0; kc < 256; kc += 32) {
        #pragma unroll
        for (int cc = 0; cc < 2; cc++) {
            int ch  = t + 256 * cc;          // 512 chunks of u16x8
            int row = ch >> 2;
            int c8  = (ch & 3) * 8;
            // A: q row with on-the-fly w1 scaling
            int Mr = M0 + row;
            int oo = Mr / Nc;
            int nn = Mr - oo * Nc;
            float wsc = w1s[oo * 8 + ((kc + c8) >> 5)];
            u16x8 va = *reinterpret_cast<const u16x8*>(
                &qsb[((size_t)gb * Nc + nn) * 256 + kc + c8]);
            u16x8 sa;
            #pragma unroll
            for (int q = 0; q < 8; q++) sa[q] = f2bf(bf2f(va[q]) * wsc);
            *reinterpret_cast<u16x4*>(&Asb[row][c8])     = (u16x4){sa[0],sa[1],sa[2],sa[3]};
            *reinterpret_cast<u16x4*>(&Asb[row][c8 + 4]) = (u16x4){sa[4],sa[5],sa[6],sa[7]};
            // B: Kt rows m (guard vs 784)
            u16x8 vb;
            if (m0 + row < Nc)
                vb = *reinterpret_cast<const u16x8*>(
                    &Kt[((size_t)gb * Nc + m0 + row) * 256 + kc + c8]);
            else
                #pragma unroll
                for (int q = 0; q < 8; q++) vb[q] = 0;
            *reinterpret_cast<u16x4*>(&Bsb[row][c8])     = (u16x4){vb[0],vb[1],vb[2],vb[3]};
            *reinterpret_cast<u16x4*>(&Bsb[row][c8 + 4]) = (u16x4){vb[4],vb[5],vb[6],vb[7]};
        }
        __syncthreads();
        #pragma unroll
        for (int k0 = 0; k0 < 32; k0 += 16) {
            s16x8 af[2], bf[2];
            #pragma unroll
            for (int di = 0; di < 2; di++)
                af[di] = ldfrag(&Asb[Msub * 64 + di * 32 + lrow][k0 + lhalf * 8]);
            #pragma unroll
            for (int ni = 0; ni < 2; ni++)
                bf[ni] = ldfrag(&Bsb[msub * 64 + ni * 32 + lrow][k0 + lhalf * 8]);
            #pragma unroll
            for (int di = 0; di < 2; di++)
                #pragma unroll
                for (int ni = 0; ni < 2; ni++)
                    acc[di][ni] = mfma32(af[di], bf[ni], acc[di][ni]);
        }
        __syncthreads();
    }

    #pragma unroll
    for (int di = 0; di < 2; di++) {
        #pragma unroll
        for (int ni = 0; ni < 2; ni++) {
            int mcol = m0 + msub * 64 + ni * 32 + lrow;
            if (mcol >= Nc) continue;
            int Mbase = M0 + Msub * 64 + di * 32;
            #pragma unroll
            for (int reg = 0; reg < 16; reg++) {
                int Mr = Mbase + (reg & 3) + 8 * (reg >> 2) + 4 * lhalf;
                float v = acc[di][ni][reg] + mbias[(size_t)Mr * Nc + mcol];
                SSb[((size_t)lb * Mrows + Mr) * Nc + mcol] = f2bf(v);
            }
        }
    }
}

// ---------------------------------------------------------------------------
// Fused softmax + talking-heads-2, in place on SSb. One block per (lb,n).
// ---------------------------------------------------------------------------
__global__ __launch_bounds__(256) void smth2_kernel(
    u16* __restrict__ SSb, const float* __restrict__ w2,
    const float* __restrict__ b2)
{
    __shared__ float Srow[8][Nc];
    __shared__ float w2s[64], b2s[8], mxs[8], invs[8];
    const int t = threadIdx.x;
    const int n = blockIdx.x;
    const int b = blockIdx.y;            // local batch
    if (t < 64) w2s[t] = w2[t];
    if (t < 8)  b2s[t] = b2[t];

    for (int ch = t; ch < 784; ch += 256) {      // 8 rows x 98 u16x8 chunks
        int i  = ch / 98;
        int m8 = (ch - i * 98) * 8;
        u16x8 u = *reinterpret_cast<const u16x8*>(
            &SSb[((size_t)b * Mrows + i * Nc + n) * Nc + m8]);
        #pragma unroll
        for (int q = 0; q < 8; q++) Srow[i][m8 + q] = bf2f(u[q]);
    }
    __syncthreads();

    {
        const int w = t >> 6, l = t & 63;
        float vals[13];
        #pragma unroll
        for (int rr = 0; rr < 2; rr++) {
            int i = w * 2 + rr;
            float mx = -1e30f;
            #pragma unroll
            for (int it = 0; it < 13; it++) {
                int m = l + it * 64;
                vals[it] = (m < Nc) ? Srow[i][m] : -1e30f;
                mx = fmaxf(mx, vals[it]);
            }
            #pragma unroll
            for (int off = 32; off; off >>= 1) mx = fmaxf(mx, __shfl_xor(mx, off));
            float sm = 0.f;
            #pragma unroll
            for (int it = 0; it < 13; it++) sm += __expf(vals[it] - mx);
            #pragma unroll
            for (int off = 32; off; off >>= 1) sm += __shfl_xor(sm, off);
            if (l == 0) { mxs[i] = mx; invs[i] = 1.0f / sm; }
        }
    }
    __syncthreads();

    for (int m = t; m < Nc; m += 256) {
        float p[8];
        #pragma unroll
        for (int i = 0; i < 8; i++)
            p[i] = __expf(Srow[i][m] - mxs[i]) * invs[i];
        #pragma unroll
        for (int o = 0; o < 8; o++) {
            float s = b2s[o];
            #pragma unroll
            for (int i = 0; i < 8; i++) s += w2s[o * 8 + i] * p[i];
            SSb[((size_t)b * Mrows + o * Nc + n) * Nc + m] = f2bf(s);
        }
    }
}

// ---------------------------------------------------------------------------
// PV: atto[gb][o*128+d][n] = sum_m P2[o,n,m] * v[o,m,d], bf16 out.
// A = V^T (d x m), B = P2^T (n x m), C cols = n -> coalesced-ish stores.
// ---------------------------------------------------------------------------
__global__ __launch_bounds__(256) void pv_kernel(
    const u16* __restrict__ SSb, const u16* __restrict__ vnat,
    u16* __restrict__ attob, int b0)
{
    __shared__ u16 Vsb[128][36];   // [d][m]
    __shared__ u16 Psb[128][36];   // [n][m]
    const int t  = threadIdx.x;
    const int n0 = blockIdx.x * 128;
    const int o  = blockIdx.y;
    const int lb = blockIdx.z;
    const int gb = b0 + lb;
    const int w = t >> 6, l = t & 63;
    const int lrow = l & 31, lhalf = l >> 5;
    const int dsub = w & 1, nsub = w >> 1;

    f32x16 acc[2][2];
    acc[0][0] = zero16(); acc[0][1] = zero16();
    acc[1][0] = zero16(); acc[1][1] = zero16();

    for (int mc = 0; mc < 800; mc += 32) {
        #pragma unroll
        for (int cc = 0; cc < 2; cc++) {
            int ch  = t + 256 * cc;
            int row = ch >> 2;
            int c8  = (ch & 3) * 8;
            bool mok = (mc + c8 < Nc);           // whole 8-chunk in/out (784%8==0)
            u16x8 vv, pp;
            if (mok)
                vv = *reinterpret_cast<const u16x8*>(
                    &vnat[((size_t)gb * DHc + o * Dc + row) * Nc + mc + c8]);
            else
                #pragma unroll
                for (int q = 0; q < 8; q++) vv[q] = 0;
            if (mok && (n0 + row < Nc))
                pp = *reinterpret_cast<const u16x8*>(
                    &SSb[((size_t)lb * Mrows + o * Nc + n0 + row) * Nc + mc + c8]);
            else
                #pragma unroll
                for (int q = 0; q < 8; q++) pp[q] = 0;
            *reinterpret_cast<u16x4*>(&Vsb[row][c8])     = (u16x4){vv[0],vv[1],vv[2],vv[3]};
            *reinterpret_cast<u16x4*>(&Vsb[row][c8 + 4]) = (u16x4){vv[4],vv[5],vv[6],vv[7]};
            *reinterpret_cast<u16x4*>(&Psb[row][c8])     = (u16x4){pp[0],pp[1],pp[2],pp[3]};
            *reinterpret_cast<u16x4*>(&Psb[row][c8 + 4]) = (u16x4){pp[4],pp[5],pp[6],pp[7]};
        }
        __syncthreads();
        #pragma unroll
        for (int k0 = 0; k0 < 32; k0 += 16) {
            s16x8 af[2], bf[2];
            #pragma unroll
            for (int di = 0; di < 2; di++)
                af[di] = ldfrag(&Vsb[dsub * 64 + di * 32 + lrow][k0 + lhalf * 8]);
            #pragma unroll
            for (int ni = 0; ni < 2; ni++)
                bf[ni] = ldfrag(&Psb[nsub * 64 + ni * 32 + lrow][k0 + lhalf * 8]);
            #pragma unroll
            for (int di = 0; di < 2; di++)
                #pragma unroll
                for (int ni = 0; ni < 2; ni++)
                    acc[di][ni] = mfma32(af[di], bf[ni], acc[di][ni]);
        }
        __syncthreads();
    }

    #pragma unroll
    for (int di = 0; di < 2; di++) {
        #pragma unroll
        for (int ni = 0; ni < 2; ni++) {
            int ncol = n0 + nsub * 64 + ni * 32 + lrow;
            if (ncol >= Nc) continue;
            int dbase = dsub * 64 + di * 32;
            #pragma unroll
            for (int reg = 0; reg < 16; reg++) {
                int d = dbase + (reg & 3) + 8 * (reg >> 2) + 4 * lhalf;
                attob[((size_t)gb * DHc + o * Dc + d) * Nc + ncol] =
                    f2bf(acc[di][ni][reg]);
            }
        }
    }
}

// ---------------------------------------------------------------------------
extern "C" void kernel_launch(void* const* d_in, const int* in_sizes, int n_in,
                              void* d_out, int out_size, void* d_ws, size_t ws_size,
                              hipStream_t stream)
{
    const float* x    = (const float*)d_in[0];
    const float* q_w  = (const float*)d_in[1];
    const float* q_b  = (const float*)d_in[2];
    const float* q_g  = (const float*)d_in[3];
    const float* q_be = (const float*)d_in[4];
    const float* q_m  = (const float*)d_in[5];
    const float* q_rv = (const float*)d_in[6];
    const float* k_w  = (const float*)d_in[7];
    const float* k_b  = (const float*)d_in[8];
    const float* k_g  = (const float*)d_in[9];
    const float* k_be = (const float*)d_in[10];
    const float* k_m  = (const float*)d_in[11];
    const float* k_rv = (const float*)d_in[12];
    const float* v_w  = (const float*)d_in[13];
    const float* v_b  = (const float*)d_in[14];
    const float* v_g  = (const float*)d_in[15];
    const float* v_be = (const float*)d_in[16];
    const float* v_m  = (const float*)d_in[17];
    const float* v_rv = (const float*)d_in[18];
    const float* vl_w = (const float*)d_in[19];
    const float* vl_b = (const float*)d_in[20];
    const float* vl_g = (const float*)d_in[21];
    const float* vl_be= (const float*)d_in[22];
    const float* vl_m = (const float*)d_in[23];
    const float* vl_rv= (const float*)d_in[24];
    const float* th1w = (const float*)d_in[25];
    const float* th1b = (const float*)d_in[26];
    const float* th2w = (const float*)d_in[27];
    const float* th2b = (const float*)d_in[28];
    const float* p_w  = (const float*)d_in[29];
    const float* p_b  = (const float*)d_in[30];
    const float* p_g  = (const float*)d_in[31];
    const float* p_be = (const float*)d_in[32];
    const float* p_m  = (const float*)d_in[33];
    const float* p_rv = (const float*)d_in[34];
    const float* btab = (const float*)d_in[35];
    const int*   bidx = (const int*)d_in[36];

    // workspace: 19.7+6.4+6.4+25.7+25.7+39.3+25.7 = 148.9 MB  (< 179.8 proven)
    char* wsb = (char*)d_ws;
    float* mbias = (float*)wsb;                  wsb += (size_t)8 * Nc * Nc * 4;
    u16*   qsb   = (u16*)wsb;                    wsb += (size_t)Bc * Nc * 256 * 2;
    u16*   Kt    = (u16*)wsb;                    wsb += (size_t)Bc * Nc * 256 * 2;
    u16*   vnat  = (u16*)wsb;                    wsb += (size_t)Bc * DHc * Nc * 2;
    u16*   vloc  = (u16*)wsb;                    wsb += (size_t)Bc * DHc * Nc * 2;
    u16*   SSb   = (u16*)wsb;                    wsb += (size_t)BPASS * Mrows * Nc * 2;
    u16*   atto  = (u16*)wsb;                    wsb += (size_t)Bc * DHc * Nc * 2;

    bias_mix_kernel<<<dim3((Nc * (Nc / 4) + 255) / 256), 256, 0, stream>>>(
        btab, bidx, th1w, th1b, mbias);
    gemm_bn<1><<<dim3(196, 4), 256, 0, stream>>>(
        q_w, x, nullptr, nullptr, q_b, q_g, q_be, q_m, q_rv, SCALEf,
        nullptr, qsb, 256, DIMc);
    gemm_bn<1><<<dim3(196, 4), 256, 0, stream>>>(
        k_w, x, nullptr, nullptr, k_b, k_g, k_be, k_m, k_rv, 1.0f,
        nullptr, Kt, 256, DIMc);
    gemm_bn<2><<<dim3(196, 16), 256, 0, stream>>>(
        v_w, x, nullptr, nullptr, v_b, v_g, v_be, v_m, v_rv, 1.0f,
        nullptr, vnat, DHc, DIMc);
    dwconv_bn_kernel<<<dim3(Bc * DHc), 256, 0, stream>>>(
        vnat, vl_w, vl_b, vl_g, vl_be, vl_m, vl_rv, vloc);
    for (int b0 = 0; b0 < Bc; b0 += BPASS) {
        scores_kernel<<<dim3(7, 49, BPASS), 256, 0, stream>>>(
            qsb, Kt, th1w, mbias, SSb, b0);
        smth2_kernel<<<dim3(Nc, BPASS), 256, 0, stream>>>(SSb, th2w, th2b);
        pv_kernel<<<dim3(7, 8, BPASS), 256, 0, stream>>>(SSb, vnat, atto, b0);
    }
    gemm_bn<3><<<dim3(196, 6), 256, 0, stream>>>(
        p_w, nullptr, atto, vloc, p_b, p_g, p_be, p_m, p_rv, 1.0f,
        (float*)d_out, nullptr, DIMc, DHc);
}

// Round 6
// 588.930 us; speedup vs baseline: 5.0830x; 1.4528x over previous
//
#include <hip/hip_runtime.h>
#include <hip/hip_bf16.h>

typedef unsigned short u16;
typedef u16   u16x4 __attribute__((ext_vector_type(4)));
typedef u16   u16x8 __attribute__((ext_vector_type(8)));
typedef short s16x4 __attribute__((ext_vector_type(4)));
typedef short s16x8 __attribute__((ext_vector_type(8)));
typedef float f32x16 __attribute__((ext_vector_type(16)));

constexpr int Bc   = 16;
constexpr int DIMc = 384;
constexpr int Rc   = 28;
constexpr int NHc  = 8;
constexpr int KDc  = 32;
constexpr int Dc   = 128;
constexpr int DHc  = 1024;   // NH*D
constexpr int Nc   = 784;    // R*R
constexpr int Mrows = NHc * Nc;  // 6272 = flattened (o,n) rows per batch
constexpr int BPASS = 4;         // batches per attention pass (SSb reuse)
constexpr float SCALEf = 0.17677669529663687f;  // 32^-0.5
constexpr float EPSf   = 1e-5f;

__device__ inline float bf2f(u16 u) {
    union { float f; unsigned i; } c; c.i = ((unsigned)u) << 16; return c.f;
}
__device__ inline u16 f2bf(float f) {
    union { float f; unsigned u; } c; c.f = f;
    unsigned r = c.u + 0x7fffu + ((c.u >> 16) & 1u);   // RNE
    return (u16)(r >> 16);
}
__device__ inline f32x16 zero16() {
    f32x16 z;
    #pragma unroll
    for (int i = 0; i < 16; i++) z[i] = 0.f;
    return z;
}
__device__ inline s16x8 ldfrag(const u16* p) {
    s16x4 lo = *(const s16x4*)p;
    s16x4 hi = *(const s16x4*)(p + 4);
    return __builtin_shufflevector(lo, hi, 0, 1, 2, 3, 4, 5, 6, 7);
}
__device__ inline f32x16 mfma32(s16x8 a, s16x8 b, f32x16 c) {
    return __builtin_amdgcn_mfma_f32_32x32x16_bf16(a, b, c, 0, 0, 0);
}

// ---------------------------------------------------------------------------
// mbias[o*784+n][m] = sum_i th1w[o,i]*btab[i, bidx[n,m]] + th1b[o]   (fp32)
// ---------------------------------------------------------------------------
__global__ __launch_bounds__(256) void bias_mix_kernel(
    const float* __restrict__ btab, const int* __restrict__ bidx,
    const float* __restrict__ w1, const float* __restrict__ b1,
    float* __restrict__ mbias)
{
    __shared__ float w1s[64], b1s[8];
    const int t = threadIdx.x;
    if (t < 64) w1s[t] = w1[t];
    if (t < 8)  b1s[t] = b1[t];
    __syncthreads();
    int e = blockIdx.x * 256 + t;          // quad index over n*196
    if (e >= Nc * (Nc / 4)) return;
    int n  = e / (Nc / 4);
    int mq = (e - n * (Nc / 4)) * 4;
    int4 g = *reinterpret_cast<const int4*>(&bidx[n * Nc + mq]);
    float gv[8][4];
    #pragma unroll
    for (int i = 0; i < 8; i++) {
        gv[i][0] = btab[i * Nc + g.x];
        gv[i][1] = btab[i * Nc + g.y];
        gv[i][2] = btab[i * Nc + g.z];
        gv[i][3] = btab[i * Nc + g.w];
    }
    #pragma unroll
    for (int o = 0; o < 8; o++) {
        float4 r;
        float* rp = &r.x;
        #pragma unroll
        for (int q = 0; q < 4; q++) {
            float s = b1s[o];
            #pragma unroll
            for (int i = 0; i < 8; i++) s += w1s[o * 8 + i] * gv[i][q];
            rp[q] = s;
        }
        *reinterpret_cast<float4*>(&mbias[((size_t)o * Nc + n) * Nc + mq]) = r;
    }
}

// ---------------------------------------------------------------------------
// Fold BN (and extra scale) into bf16 weights + fp32 bias.
//   Wb[o][k] = bf16(sc * inv[o] * W[o][k]); bb[o] = sc*((b-m)*inv + beta)
// ---------------------------------------------------------------------------
__global__ __launch_bounds__(256) void fold_w_kernel(
    const float* __restrict__ W, const float* __restrict__ b,
    const float* __restrict__ g, const float* __restrict__ bet,
    const float* __restrict__ m, const float* __restrict__ rv,
    float sc, u16* __restrict__ Wb, float* __restrict__ bb, int O, int K)
{
    int i = blockIdx.x * 256 + threadIdx.x;
    if (i >= O * K) return;
    int o = i / K;
    float inv = g[o] / sqrtf(rv[o] + EPSf);
    Wb[i] = f2bf(W[i] * inv * sc);
    if (i - o * K == 0) bb[o] = ((b[o] - m[o]) * inv + bet[o]) * sc;
}

// ---------------------------------------------------------------------------
// Cast + transpose x: xT[b][n][c] bf16 from x[b][c][n] fp32. 64x64 LDS tiles.
// ---------------------------------------------------------------------------
__global__ __launch_bounds__(256) void castx_kernel(
    const float* __restrict__ x, u16* __restrict__ xT)
{
    __shared__ float tile[64][65];
    const int t = threadIdx.x;
    const int n0 = blockIdx.x * 64;
    const int c0 = blockIdx.y * 64;
    const int b  = blockIdx.z;
    const int jj = (t & 15) * 4, ii = t >> 4;
    #pragma unroll
    for (int rep = 0; rep < 4; rep++) {
        int c = c0 + ii + rep * 16;
        if (n0 + jj < Nc) {
            float4 v = *reinterpret_cast<const float4*>(
                &x[((size_t)b * DIMc + c) * Nc + n0 + jj]);
            tile[ii + rep * 16][jj + 0] = v.x;
            tile[ii + rep * 16][jj + 1] = v.y;
            tile[ii + rep * 16][jj + 2] = v.z;
            tile[ii + rep * 16][jj + 3] = v.w;
        }
    }
    __syncthreads();
    const int cc = (t & 15) * 4;
    #pragma unroll
    for (int rep = 0; rep < 4; rep++) {
        int nn = (t >> 4) + rep * 16;
        int n  = n0 + nn;
        if (n < Nc) {
            u16x4 r;
            #pragma unroll
            for (int q = 0; q < 4; q++) r[q] = f2bf(tile[cc + q][nn]);
            *reinterpret_cast<u16x4*>(&xT[((size_t)b * Nc + n) * DIMc + c0 + cc]) = r;
        }
    }
}

// ---------------------------------------------------------------------------
// Unified bf16 MFMA GEMM: C[row][col] = sum_k A[row][k]*B[col][k] + bias.
// 128x128 tile, 4 waves (2x2 64x64 quadrants), BK=32. A rows never guarded
// (all M dims are multiples of 128); B rows guarded by Bvalid when BGUARD.
// ---------------------------------------------------------------------------
template<int KK, bool BGUARD, bool BIAS_COL, bool OUTF32>
__global__ __launch_bounds__(256) void mfma_gemm(
    const u16* __restrict__ A, const u16* __restrict__ B,
    const float* __restrict__ bias, u16* __restrict__ Cb,
    float* __restrict__ Cf, size_t zB, size_t zC, int ldC, int Bvalid)
{
    __shared__ u16 Asb[128][36];
    __shared__ u16 Bsb[128][36];
    const int t    = threadIdx.x;
    const int col0 = blockIdx.x * 128;
    const int A0   = blockIdx.y * 128;
    const int z    = blockIdx.z;
    const u16* Bz  = B + zB * (size_t)z;
    const int w = t >> 6, l = t & 63;
    const int lrow = l & 31, lhalf = l >> 5;
    const int rsub = w & 1, csub = w >> 1;

    f32x16 acc[2][2];
    acc[0][0] = zero16(); acc[0][1] = zero16();
    acc[1][0] = zero16(); acc[1][1] = zero16();

    for (int kc = 0; kc < KK; kc += 32) {
        #pragma unroll
        for (int cc = 0; cc < 2; cc++) {
            int ch  = t + 256 * cc;
            int row = ch >> 2;
            int c8  = (ch & 3) * 8;
            u16x8 va = *reinterpret_cast<const u16x8*>(
                &A[(size_t)(A0 + row) * KK + kc + c8]);
            *reinterpret_cast<u16x4*>(&Asb[row][c8])     = (u16x4){va[0],va[1],va[2],va[3]};
            *reinterpret_cast<u16x4*>(&Asb[row][c8 + 4]) = (u16x4){va[4],va[5],va[6],va[7]};
            u16x8 vb;
            if (!BGUARD || col0 + row < Bvalid)
                vb = *reinterpret_cast<const u16x8*>(
                    &Bz[(size_t)(col0 + row) * KK + kc + c8]);
            else
                #pragma unroll
                for (int q = 0; q < 8; q++) vb[q] = 0;
            *reinterpret_cast<u16x4*>(&Bsb[row][c8])     = (u16x4){vb[0],vb[1],vb[2],vb[3]};
            *reinterpret_cast<u16x4*>(&Bsb[row][c8 + 4]) = (u16x4){vb[4],vb[5],vb[6],vb[7]};
        }
        __syncthreads();
        #pragma unroll
        for (int k0 = 0; k0 < 32; k0 += 16) {
            s16x8 af[2], bf[2];
            #pragma unroll
            for (int di = 0; di < 2; di++)
                af[di] = ldfrag(&Asb[rsub * 64 + di * 32 + lrow][k0 + lhalf * 8]);
            #pragma unroll
            for (int ni = 0; ni < 2; ni++)
                bf[ni] = ldfrag(&Bsb[csub * 64 + ni * 32 + lrow][k0 + lhalf * 8]);
            #pragma unroll
            for (int di = 0; di < 2; di++)
                #pragma unroll
                for (int ni = 0; ni < 2; ni++)
                    acc[di][ni] = mfma32(af[di], bf[ni], acc[di][ni]);
        }
        __syncthreads();
    }

    #pragma unroll
    for (int di = 0; di < 2; di++) {
        #pragma unroll
        for (int ni = 0; ni < 2; ni++) {
            int col = col0 + csub * 64 + ni * 32 + lrow;
            if (BGUARD && col >= Bvalid) continue;
            float bcol = BIAS_COL ? bias[col] : 0.f;
            #pragma unroll
            for (int reg = 0; reg < 16; reg++) {
                int row = A0 + rsub * 64 + di * 32 + (reg & 3) + 8 * (reg >> 2) + 4 * lhalf;
                float val = acc[di][ni][reg] + (BIAS_COL ? bcol : bias[row]);
                size_t off = zC * (size_t)z + (size_t)row * ldC + col;
                if constexpr (OUTF32) Cf[off] = val;
                else                  Cb[off] = f2bf(val);
            }
        }
    }
}

// ---------------------------------------------------------------------------
// Depthwise 3x3 + BN, natural layout, bf16 in/out. One block per (b,c).
// ---------------------------------------------------------------------------
__global__ __launch_bounds__(256) void dwconv_bn_kernel(
    const u16* __restrict__ vnat, const float* __restrict__ wl,
    const float* __restrict__ bl, const float* __restrict__ gg,
    const float* __restrict__ bet, const float* __restrict__ mea,
    const float* __restrict__ rvv, u16* __restrict__ vloc)
{
    __shared__ float img[30][30];
    const int t = threadIdx.x;
    const int b = blockIdx.x >> 10;
    const int c = blockIdx.x & 1023;
    const u16* src = vnat + ((size_t)b * DHc + c) * Nc;

    for (int i = t; i < 900; i += 256) img[i / 30][i % 30] = 0.f;
    __syncthreads();
    if (t < 196) {
        u16x4 u = *reinterpret_cast<const u16x4*>(&src[t * 4]);
        int y = (t * 4) / 28, x = (t * 4) % 28;
        img[y + 1][x + 1] = bf2f(u[0]);
        img[y + 1][x + 2] = bf2f(u[1]);
        img[y + 1][x + 3] = bf2f(u[2]);
        img[y + 1][x + 4] = bf2f(u[3]);
    }
    __syncthreads();

    float wreg[9];
    #pragma unroll
    for (int i = 0; i < 9; i++) wreg[i] = wl[c * 9 + i];
    float inv = gg[c] / sqrtf(rvv[c] + EPSf);
    float sh  = bet[c] - mea[c] * inv + bl[c] * inv;

    for (int i = t; i < Nc; i += 256) {
        int y = i / 28, x = i % 28;
        float a = 0.f;
        #pragma unroll
        for (int dy = 0; dy < 3; dy++)
            #pragma unroll
            for (int dx = 0; dx < 3; dx++)
                a += img[y + dy][x + dx] * wreg[dy * 3 + dx];
        vloc[((size_t)b * DHc + c) * Nc + i] = f2bf(a * inv + sh);
    }
}

// ---------------------------------------------------------------------------
// Scores with folded TH1:
//   SS[lb][Mr][m] = sum_ik w1[o, ik>>5]*qs[gb][n][ik] * Kt[gb][m][ik] + mbias
// ---------------------------------------------------------------------------
__global__ __launch_bounds__(256) void scores_kernel(
    const u16* __restrict__ qsb, const u16* __restrict__ Kt,
    const float* __restrict__ th1w, const float* __restrict__ mbias,
    u16* __restrict__ SSb, int b0)
{
    __shared__ u16 Asb[128][36];
    __shared__ u16 Bsb[128][36];
    __shared__ float w1s[64];
    const int t  = threadIdx.x;
    const int m0 = blockIdx.x * 128;
    const int M0 = blockIdx.y * 128;
    const int lb = blockIdx.z;
    const int gb = b0 + lb;
    const int w = t >> 6, l = t & 63;
    const int lrow = l & 31, lhalf = l >> 5;
    const int Msub = w & 1, msub = w >> 1;

    if (t < 64) w1s[t] = th1w[t];
    __syncthreads();

    f32x16 acc[2][2];
    acc[0][0] = zero16(); acc[0][1] = zero16();
    acc[1][0] = zero16(); acc[1][1] = zero16();

    for (int kc = 0; kc < 256; kc += 32) {
        #pragma unroll
        for (int cc = 0; cc < 2; cc++) {
            int ch  = t + 256 * cc;
            int row = ch >> 2;
            int c8  = (ch & 3) * 8;
            int Mr = M0 + row;
            int oo = Mr / Nc;
            int nn = Mr - oo * Nc;
            float wsc = w1s[oo * 8 + ((kc + c8) >> 5)];
            u16x8 va = *reinterpret_cast<const u16x8*>(
                &qsb[((size_t)gb * Nc + nn) * 256 + kc + c8]);
            u16x8 sa;
            #pragma unroll
            for (int q = 0; q < 8; q++) sa[q] = f2bf(bf2f(va[q]) * wsc);
            *reinterpret_cast<u16x4*>(&Asb[row][c8])     = (u16x4){sa[0],sa[1],sa[2],sa[3]};
            *reinterpret_cast<u16x4*>(&Asb[row][c8 + 4]) = (u16x4){sa[4],sa[5],sa[6],sa[7]};
            u16x8 vb;
            if (m0 + row < Nc)
                vb = *reinterpret_cast<const u16x8*>(
                    &Kt[((size_t)gb * Nc + m0 + row) * 256 + kc + c8]);
            else
                #pragma unroll
                for (int q = 0; q < 8; q++) vb[q] = 0;
            *reinterpret_cast<u16x4*>(&Bsb[row][c8])     = (u16x4){vb[0],vb[1],vb[2],vb[3]};
            *reinterpret_cast<u16x4*>(&Bsb[row][c8 + 4]) = (u16x4){vb[4],vb[5],vb[6],vb[7]};
        }
        __syncthreads();
        #pragma unroll
        for (int k0 = 0; k0 < 32; k0 += 16) {
            s16x8 af[2], bf[2];
            #pragma unroll
            for (int di = 0; di < 2; di++)
                af[di] = ldfrag(&Asb[Msub * 64 + di * 32 + lrow][k0 + lhalf * 8]);
            #pragma unroll
            for (int ni = 0; ni < 2; ni++)
                bf[ni] = ldfrag(&Bsb[msub * 64 + ni * 32 + lrow][k0 + lhalf * 8]);
            #pragma unroll
            for (int di = 0; di < 2; di++)
                #pragma unroll
                for (int ni = 0; ni < 2; ni++)
                    acc[di][ni] = mfma32(af[di], bf[ni], acc[di][ni]);
        }
        __syncthreads();
    }

    #pragma unroll
    for (int di = 0; di < 2; di++) {
        #pragma unroll
        for (int ni = 0; ni < 2; ni++) {
            int mcol = m0 + msub * 64 + ni * 32 + lrow;
            if (mcol >= Nc) continue;
            int Mbase = M0 + Msub * 64 + di * 32;
            #pragma unroll
            for (int reg = 0; reg < 16; reg++) {
                int Mr = Mbase + (reg & 3) + 8 * (reg >> 2) + 4 * lhalf;
                float v = acc[di][ni][reg] + mbias[(size_t)Mr * Nc + mcol];
                SSb[((size_t)lb * Mrows + Mr) * Nc + mcol] = f2bf(v);
            }
        }
    }
}

// ---------------------------------------------------------------------------
// Fused softmax + talking-heads-2, in place on SSb. One block per (lb,n).
// ---------------------------------------------------------------------------
__global__ __launch_bounds__(256) void smth2_kernel(
    u16* __restrict__ SSb, const float* __restrict__ w2,
    const float* __restrict__ b2)
{
    __shared__ float Srow[8][Nc];
    __shared__ float w2s[64], b2s[8], mxs[8], invs[8];
    const int t = threadIdx.x;
    const int n = blockIdx.x;
    const int b = blockIdx.y;
    if (t < 64) w2s[t] = w2[t];
    if (t < 8)  b2s[t] = b2[t];

    for (int ch = t; ch < 784; ch += 256) {
        int i  = ch / 98;
        int m8 = (ch - i * 98) * 8;
        u16x8 u = *reinterpret_cast<const u16x8*>(
            &SSb[((size_t)b * Mrows + i * Nc + n) * Nc + m8]);
        #pragma unroll
        for (int q = 0; q < 8; q++) Srow[i][m8 + q] = bf2f(u[q]);
    }
    __syncthreads();

    {
        const int w = t >> 6, l = t & 63;
        float vals[13];
        #pragma unroll
        for (int rr = 0; rr < 2; rr++) {
            int i = w * 2 + rr;
            float mx = -1e30f;
            #pragma unroll
            for (int it = 0; it < 13; it++) {
                int m = l + it * 64;
                vals[it] = (m < Nc) ? Srow[i][m] : -1e30f;
                mx = fmaxf(mx, vals[it]);
            }
            #pragma unroll
            for (int off = 32; off; off >>= 1) mx = fmaxf(mx, __shfl_xor(mx, off));
            float sm = 0.f;
            #pragma unroll
            for (int it = 0; it < 13; it++) sm += __expf(vals[it] - mx);
            #pragma unroll
            for (int off = 32; off; off >>= 1) sm += __shfl_xor(sm, off);
            if (l == 0) { mxs[i] = mx; invs[i] = 1.0f / sm; }
        }
    }
    __syncthreads();

    for (int m = t; m < Nc; m += 256) {
        float p[8];
        #pragma unroll
        for (int i = 0; i < 8; i++)
            p[i] = __expf(Srow[i][m] - mxs[i]) * invs[i];
        #pragma unroll
        for (int o = 0; o < 8; o++) {
            float s = b2s[o];
            #pragma unroll
            for (int i = 0; i < 8; i++) s += w2s[o * 8 + i] * p[i];
            SSb[((size_t)b * Mrows + o * Nc + n) * Nc + m] = f2bf(s);
        }
    }
}

// ---------------------------------------------------------------------------
// PV: attoT[gb][n][o*128+d] = sum_m P2[o,n,m] * v[o,m,d], bf16 out.
// C rows = n (A = P2), cols = d (B = V^T) -> lane-contiguous d stores.
// ---------------------------------------------------------------------------
__global__ __launch_bounds__(256) void pv_kernel(
    const u16* __restrict__ SSb, const u16* __restrict__ vnat,
    u16* __restrict__ attoT, int b0)
{
    __shared__ u16 Vsb[128][36];   // [d][m]
    __shared__ u16 Psb[128][36];   // [n][m]
    const int t  = threadIdx.x;
    const int n0 = blockIdx.x * 128;
    const int o  = blockIdx.y;
    const int lb = blockIdx.z;
    const int gb = b0 + lb;
    const int w = t >> 6, l = t & 63;
    const int lrow = l & 31, lhalf = l >> 5;
    const int nsub = w & 1, dsub = w >> 1;

    f32x16 acc[2][2];
    acc[0][0] = zero16(); acc[0][1] = zero16();
    acc[1][0] = zero16(); acc[1][1] = zero16();

    for (int mc = 0; mc < 800; mc += 32) {
        #pragma unroll
        for (int cc = 0; cc < 2; cc++) {
            int ch  = t + 256 * cc;
            int row = ch >> 2;
            int c8  = (ch & 3) * 8;
            bool mok = (mc + c8 < Nc);
            u16x8 vv, pp;
            if (mok)
                vv = *reinterpret_cast<const u16x8*>(
                    &vnat[((size_t)gb * DHc + o * Dc + row) * Nc + mc + c8]);
            else
                #pragma unroll
                for (int q = 0; q < 8; q++) vv[q] = 0;
            if (mok && (n0 + row < Nc))
                pp = *reinterpret_cast<const u16x8*>(
                    &SSb[((size_t)lb * Mrows + o * Nc + n0 + row) * Nc + mc + c8]);
            else
                #pragma unroll
                for (int q = 0; q < 8; q++) pp[q] = 0;
            *reinterpret_cast<u16x4*>(&Vsb[row][c8])     = (u16x4){vv[0],vv[1],vv[2],vv[3]};
            *reinterpret_cast<u16x4*>(&Vsb[row][c8 + 4]) = (u16x4){vv[4],vv[5],vv[6],vv[7]};
            *reinterpret_cast<u16x4*>(&Psb[row][c8])     = (u16x4){pp[0],pp[1],pp[2],pp[3]};
            *reinterpret_cast<u16x4*>(&Psb[row][c8 + 4]) = (u16x4){pp[4],pp[5],pp[6],pp[7]};
        }
        __syncthreads();
        #pragma unroll
        for (int k0 = 0; k0 < 32; k0 += 16) {
            s16x8 af[2], bf[2];
            #pragma unroll
            for (int di = 0; di < 2; di++)
                af[di] = ldfrag(&Psb[nsub * 64 + di * 32 + lrow][k0 + lhalf * 8]);
            #pragma unroll
            for (int ni = 0; ni < 2; ni++)
                bf[ni] = ldfrag(&Vsb[dsub * 64 + ni * 32 + lrow][k0 + lhalf * 8]);
            #pragma unroll
            for (int di = 0; di < 2; di++)
                #pragma unroll
                for (int ni = 0; ni < 2; ni++)
                    acc[di][ni] = mfma32(af[di], bf[ni], acc[di][ni]);
        }
        __syncthreads();
    }

    #pragma unroll
    for (int di = 0; di < 2; di++) {
        #pragma unroll
        for (int ni = 0; ni < 2; ni++) {
            int dcol = dsub * 64 + ni * 32 + lrow;
            #pragma unroll
            for (int reg = 0; reg < 16; reg++) {
                int nrow = n0 + nsub * 64 + di * 32 + (reg & 3) + 8 * (reg >> 2) + 4 * lhalf;
                if (nrow < Nc)
                    attoT[((size_t)gb * Nc + nrow) * DHc + o * Dc + dcol] =
                        f2bf(acc[di][ni][reg]);
            }
        }
    }
}

// ---------------------------------------------------------------------------
// pact[b][n][c] = bf16(relu(attoT[b][n][c] + vloc[b][c][n]^T)). 64x64 tiles.
// ---------------------------------------------------------------------------
__global__ __launch_bounds__(256) void prepP_kernel(
    const u16* __restrict__ attoT, const u16* __restrict__ vloc,
    u16* __restrict__ pact)
{
    __shared__ float tile[64][65];
    const int t = threadIdx.x;
    const int n0 = blockIdx.x * 64;
    const int c0 = blockIdx.y * 64;
    const int b  = blockIdx.z;
    const int jj = (t & 15) * 4, ii = t >> 4;
    #pragma unroll
    for (int rep = 0; rep < 4; rep++) {
        int c = c0 + ii + rep * 16;
        if (n0 + jj < Nc) {
            u16x4 v = *reinterpret_cast<const u16x4*>(
                &vloc[((size_t)b * DHc + c) * Nc + n0 + jj]);
            tile[ii + rep * 16][jj + 0] = bf2f(v[0]);
            tile[ii + rep * 16][jj + 1] = bf2f(v[1]);
            tile[ii + rep * 16][jj + 2] = bf2f(v[2]);
            tile[ii + rep * 16][jj + 3] = bf2f(v[3]);
        }
    }
    __syncthreads();
    const int cc = (t & 15) * 4;
    #pragma unroll
    for (int rep = 0; rep < 4; rep++) {
        int nn = (t >> 4) + rep * 16;
        int n  = n0 + nn;
        if (n < Nc) {
            size_t off = ((size_t)b * Nc + n) * DHc + c0 + cc;
            u16x4 a = *reinterpret_cast<const u16x4*>(&attoT[off]);
            u16x4 r;
            #pragma unroll
            for (int q = 0; q < 4; q++)
                r[q] = f2bf(fmaxf(bf2f(a[q]) + tile[cc + q][nn], 0.f));
            *reinterpret_cast<u16x4*>(&pact[off]) = r;
        }
    }
}

// ---------------------------------------------------------------------------
extern "C" void kernel_launch(void* const* d_in, const int* in_sizes, int n_in,
                              void* d_out, int out_size, void* d_ws, size_t ws_size,
                              hipStream_t stream)
{
    const float* x    = (const float*)d_in[0];
    const float* q_w  = (const float*)d_in[1];
    const float* q_b  = (const float*)d_in[2];
    const float* q_g  = (const float*)d_in[3];
    const float* q_be = (const float*)d_in[4];
    const float* q_m  = (const float*)d_in[5];
    const float* q_rv = (const float*)d_in[6];
    const float* k_w  = (const float*)d_in[7];
    const float* k_b  = (const float*)d_in[8];
    const float* k_g  = (const float*)d_in[9];
    const float* k_be = (const float*)d_in[10];
    const float* k_m  = (const float*)d_in[11];
    const float* k_rv = (const float*)d_in[12];
    const float* v_w  = (const float*)d_in[13];
    const float* v_b  = (const float*)d_in[14];
    const float* v_g  = (const float*)d_in[15];
    const float* v_be = (const float*)d_in[16];
    const float* v_m  = (const float*)d_in[17];
    const float* v_rv = (const float*)d_in[18];
    const float* vl_w = (const float*)d_in[19];
    const float* vl_b = (const float*)d_in[20];
    const float* vl_g = (const float*)d_in[21];
    const float* vl_be= (const float*)d_in[22];
    const float* vl_m = (const float*)d_in[23];
    const float* vl_rv= (const float*)d_in[24];
    const float* th1w = (const float*)d_in[25];
    const float* th1b = (const float*)d_in[26];
    const float* th2w = (const float*)d_in[27];
    const float* th2b = (const float*)d_in[28];
    const float* p_w  = (const float*)d_in[29];
    const float* p_b  = (const float*)d_in[30];
    const float* p_g  = (const float*)d_in[31];
    const float* p_be = (const float*)d_in[32];
    const float* p_m  = (const float*)d_in[33];
    const float* p_rv = (const float*)d_in[34];
    const float* btab = (const float*)d_in[35];
    const int*   bidx = (const int*)d_in[36];

    // ws: 19.7+9.6+6.4+6.4+25.7+25.7+39.3+25.7+2.0 = ~160.5 MB (<179.8 proven)
    char* wsb = (char*)d_ws;
    float* mbias = (float*)wsb;                  wsb += (size_t)8 * Nc * Nc * 4;
    u16*   xT    = (u16*)wsb;                    wsb += (size_t)Bc * Nc * DIMc * 2;
    u16*   qsb   = (u16*)wsb;                    wsb += (size_t)Bc * Nc * 256 * 2;
    u16*   Kt    = (u16*)wsb;                    wsb += (size_t)Bc * Nc * 256 * 2;
    u16*   vnat  = (u16*)wsb;                    wsb += (size_t)Bc * DHc * Nc * 2;
    u16*   vloc  = (u16*)wsb;                    wsb += (size_t)Bc * DHc * Nc * 2;
    u16*   SSb   = (u16*)wsb;                    wsb += (size_t)BPASS * Mrows * Nc * 2;
    u16*   attoT = (u16*)wsb;                    wsb += (size_t)Bc * DHc * Nc * 2;
    u16*   qwb   = (u16*)wsb;                    wsb += (size_t)256 * DIMc * 2;
    u16*   kwb   = (u16*)wsb;                    wsb += (size_t)256 * DIMc * 2;
    u16*   vwb   = (u16*)wsb;                    wsb += (size_t)DHc * DIMc * 2;
    u16*   pwb   = (u16*)wsb;                    wsb += (size_t)DIMc * DHc * 2;
    float* qbb   = (float*)wsb;                  wsb += 256 * 4;
    float* kbb   = (float*)wsb;                  wsb += 256 * 4;
    float* vbb   = (float*)wsb;                  wsb += DHc * 4;
    float* pbb   = (float*)wsb;                  wsb += DIMc * 4;
    u16*   pact  = SSb;   // alias: SSb dead after last pv pass

    bias_mix_kernel<<<dim3((Nc * (Nc / 4) + 255) / 256), 256, 0, stream>>>(
        btab, bidx, th1w, th1b, mbias);
    castx_kernel<<<dim3(13, 6, Bc), 256, 0, stream>>>(x, xT);
    fold_w_kernel<<<dim3((256 * DIMc + 255) / 256), 256, 0, stream>>>(
        q_w, q_b, q_g, q_be, q_m, q_rv, SCALEf, qwb, qbb, 256, DIMc);
    fold_w_kernel<<<dim3((256 * DIMc + 255) / 256), 256, 0, stream>>>(
        k_w, k_b, k_g, k_be, k_m, k_rv, 1.0f, kwb, kbb, 256, DIMc);
    fold_w_kernel<<<dim3((DHc * DIMc + 255) / 256), 256, 0, stream>>>(
        v_w, v_b, v_g, v_be, v_m, v_rv, 1.0f, vwb, vbb, DHc, DIMc);
    fold_w_kernel<<<dim3((DIMc * DHc + 255) / 256), 256, 0, stream>>>(
        p_w, p_b, p_g, p_be, p_m, p_rv, 1.0f, pwb, pbb, DIMc, DHc);

    // q/k proj: C[bn][ik] = xT @ Wb^T + bias[ik]
    mfma_gemm<DIMc, false, true, false><<<dim3(2, 98, 1), 256, 0, stream>>>(
        xT, qwb, qbb, qsb, nullptr, 0, 0, 256, 256);
    mfma_gemm<DIMc, false, true, false><<<dim3(2, 98, 1), 256, 0, stream>>>(
        xT, kwb, kbb, Kt, nullptr, 0, 0, 256, 256);
    // v proj: per batch C[c][n] = vwb @ xT[b]^T + bias[c]
    mfma_gemm<DIMc, true, false, false><<<dim3(7, 8, Bc), 256, 0, stream>>>(
        vwb, xT, vbb, vnat, nullptr, (size_t)Nc * DIMc, (size_t)DHc * Nc, Nc, Nc);

    dwconv_bn_kernel<<<dim3(Bc * DHc), 256, 0, stream>>>(
        vnat, vl_w, vl_b, vl_g, vl_be, vl_m, vl_rv, vloc);

    for (int b0 = 0; b0 < Bc; b0 += BPASS) {
        scores_kernel<<<dim3(7, 49, BPASS), 256, 0, stream>>>(
            qsb, Kt, th1w, mbias, SSb, b0);
        smth2_kernel<<<dim3(Nc, BPASS), 256, 0, stream>>>(SSb, th2w, th2b);
        pv_kernel<<<dim3(7, 8, BPASS), 256, 0, stream>>>(SSb, vnat, attoT, b0);
    }

    prepP_kernel<<<dim3(13, 16, Bc), 256, 0, stream>>>(attoT, vloc, pact);
    // p proj: per batch C[dim][n] = pwb @ pact[b]^T + bias[dim], fp32 out
    mfma_gemm<DHc, true, false, true><<<dim3(7, 3, Bc), 256, 0, stream>>>(
        pwb, pact, pbb, nullptr, (float*)d_out, (size_t)Nc * DHc,
        (size_t)DIMc * Nc, Nc, Nc);
}